// Round 15
// baseline (326.515 us; speedup 1.0000x reference)
//
#include <hip/hip_runtime.h>
#include <math.h>

typedef float f32x4 __attribute__((ext_vector_type(4)));
typedef __bf16 bf16x2 __attribute__((ext_vector_type(2)));
typedef __bf16 bf16x4 __attribute__((ext_vector_type(4)));
typedef __bf16 bf16x8 __attribute__((ext_vector_type(8)));

// ---------------------------------------------------------------------------
// GAT 2-layer forward.
// GEMM layer 1: 2-term split-bf16 MFMA (Ah@Bh + Al@Bh); layer 2: pure bf16.
// BM=32, 4 waves, fragment-major XOR-swizzled LDS A (dbuf), B fragment-major
// 1KB chunks with register prefetch, T4 barrier, launch_bounds(256,5).
// Aggregation: CSR by dst; phase A sum-exp + alpha cache in LDS; phase B
// 4x-unrolled bf16x4 gather (at memory-service ceiling, R13 null A/B).
// ---------------------------------------------------------------------------

// Pack one W[K][N] fp32 element into fragment-major bf16 1KB-chunk layout.
__device__ __forceinline__ void pack_one(const float* W, __bf16* Bh, int idx, int N) {
    int e = idx & 7;
    int l = (idx >> 3) & 63;
    int c = idx >> 9;
    int ng = N >> 4;
    int g = c % ng;
    int k0 = (c / ng) << 5;
    int col = g * 16 + (l & 15);
    int k = k0 + ((l >> 4) << 3) + e;
    Bh[idx] = (__bf16)W[(size_t)k * N + col];
}

// hist (dst-degree count) + both weight packs, one launch (independent work)
__global__ void hist_pack_kernel(const int* __restrict__ dst, int* __restrict__ cnt,
                                 int E, const float* __restrict__ W1,
                                 __bf16* __restrict__ B1, int sz1, int N1,
                                 const float* __restrict__ W2,
                                 __bf16* __restrict__ B2, int sz2, int N2) {
    int idx = blockIdx.x * blockDim.x + threadIdx.x;
    if (idx < E) atomicAdd(&cnt[dst[idx]], 1);
    if (idx < sz1) pack_one(W1, B1, idx, N1);
    else if (idx < sz1 + sz2) pack_one(W2, B2, idx - sz1, N2);
}

__global__ __launch_bounds__(256) void scan_blk(const int* __restrict__ cnt,
                                                int* __restrict__ incl,
                                                int* __restrict__ bsum, int n) {
    __shared__ int sd[256];
    const int t = threadIdx.x;
    int i = blockIdx.x * 256 + t;
    int v = (i < n) ? cnt[i] : 0;
    sd[t] = v;
    __syncthreads();
#pragma unroll
    for (int off = 1; off < 256; off <<= 1) {
        int x = (t >= off) ? sd[t - off] : 0;
        __syncthreads();
        sd[t] += x;
        __syncthreads();
    }
    if (i < n) incl[i] = sd[t];
    if (t == 255) bsum[blockIdx.x] = sd[255];
}

__global__ __launch_bounds__(256) void scan_top(const int* __restrict__ bsum,
                                                int* __restrict__ boff, int nb) {
    __shared__ int sd[256];
    const int t = threadIdx.x;
    int v = (t < nb) ? bsum[t] : 0;
    sd[t] = v;
    __syncthreads();
#pragma unroll
    for (int off = 1; off < 256; off <<= 1) {
        int x = (t >= off) ? sd[t - off] : 0;
        __syncthreads();
        sd[t] += x;
        __syncthreads();
    }
    if (t < nb) boff[t] = sd[t] - v;
}

__global__ void scan_fix(const int* __restrict__ incl, const int* __restrict__ boff,
                         const int* __restrict__ cnt, int* __restrict__ row_ptr,
                         int* __restrict__ cursor, int n) {
    int i = blockIdx.x * blockDim.x + threadIdx.x;
    if (i >= n) return;
    int total = incl[i] + boff[i >> 8];
    row_ptr[i + 1] = total;
    cursor[i] = total - cnt[i];
    if (i == 0) row_ptr[0] = 0;
}

__global__ void fill_kernel(const int* __restrict__ src, const int* __restrict__ dst,
                            int* __restrict__ cursor, int* __restrict__ ssrc, int E) {
    int e = blockIdx.x * blockDim.x + threadIdx.x;
    if (e < E) {
        int pos = atomicAdd(&cursor[dst[e]], 1);
        ssrc[pos] = src[e];
    }
}

__device__ __forceinline__ int swz6(int x) { return x ^ (x >> 3); }

// ---------------------------------------------------------------------------
// Split-bf16 MFMA GEMM + fused el/er epilogue. BM=32, 256 thr, 4 waves.
// TERMS=2, FP32A=true : layer 1.  TERMS=1, FP32A=false: layer 2.
// launch_bounds(256,5): VGPR cap 102 (actual ~70) -> 5 blocks/CU vs 4.
// ---------------------------------------------------------------------------
template <int BN, int NREP, bool FP32A, int TERMS>
__global__ __launch_bounds__(256, 5) void gemm_fused(
    const float* __restrict__ Af, const __bf16* __restrict__ Ahg,
    const __bf16* __restrict__ Bph, const float* __restrict__ al,
    const float* __restrict__ ar, __bf16* __restrict__ featb,
    float* __restrict__ el, float* __restrict__ er, int M, int K) {
    constexpr int WN = NREP * 16;  // per-wave strip; BN == 4*WN
    constexpr int D = BN / 8;      // head dim; WN == 2*D (strip = 2 heads)

    struct StageT {
        __bf16 Ah[2][2][64][8];
        __bf16 Al[2][2][64][8];  // used only when TERMS==2
    };
    union Smem {
        StageT s;
        float ctile[4][16][WN + 1];
    };
    __shared__ __align__(16) Smem u;

    const int t = threadIdx.x;
    const int lane = t & 63;
    const int wid = t >> 6;
    const int row0 = blockIdx.x * 32;
    const int colw = wid * WN;
    const int fr = lane & 15;
    const int kq = lane >> 4;
    const int sr = t >> 3;
    const int kc = (t & 7) * 4;
    const int m_s = sr >> 4;
    const int xs = (sr & 15) + 16 * (kc >> 3);
    const int e0 = kc & 7;

    float4 av;
    bf16x4 avh;

    auto loadA = [&](int k0) {
        int gr = row0 + sr;
        if (gr >= M) gr = M - 1;
        if constexpr (FP32A) {
            av = *(const float4*)&Af[(size_t)gr * K + k0 + kc];
        } else {
            avh = *(const bf16x4*)&Ahg[(size_t)gr * K + k0 + kc];
        }
    };
    auto storeA = [&](int p) {
        if constexpr (FP32A) {
            __bf16 h0 = (__bf16)av.x, h1 = (__bf16)av.y, h2 = (__bf16)av.z,
                   h3 = (__bf16)av.w;
            bf16x4 hv = {h0, h1, h2, h3};
            bf16x4 lv = {(__bf16)(av.x - (float)h0), (__bf16)(av.y - (float)h1),
                         (__bf16)(av.z - (float)h2), (__bf16)(av.w - (float)h3)};
            *(bf16x4*)&u.s.Ah[p][m_s][swz6(xs)][e0] = hv;
            *(bf16x4*)&u.s.Al[p][m_s][swz6(xs)][e0] = lv;
        } else {
            *(bf16x4*)&u.s.Ah[p][m_s][swz6(xs)][e0] = avh;
        }
    };
    auto loadB = [&](int k0, bf16x8* b) {
        const int c0 = (k0 >> 5) * (BN >> 4) + wid * NREP;
#pragma unroll
        for (int n = 0; n < NREP; ++n)
            b[n] = *(const bf16x8*)&Bph[(size_t)(c0 + n) * 512 + lane * 8];
    };

    f32x4 acc[2][NREP] = {};
    bf16x8 bh[NREP], bn[NREP];

    loadA(0);
    loadB(0, bh);
    int p = 0;
    for (int k0 = 0; k0 < K; k0 += 32) {
        storeA(p);
        const bool nxt = (k0 + 32 < K);
        if (nxt) {
            loadA(k0 + 32);      // stays in flight across barrier (vmcnt wait
            loadB(k0 + 32, bn);  // lands at first use, hidden under MFMA)
        }
        // T4: drain ONLY the LDS staging writes, then raw barrier.
        asm volatile("s_waitcnt lgkmcnt(0)" ::: "memory");
        __builtin_amdgcn_s_barrier();
        const int sl_ = swz6(lane);
        bf16x8 ah0 = *(const bf16x8*)&u.s.Ah[p][0][sl_][0];
        bf16x8 ah1 = *(const bf16x8*)&u.s.Ah[p][1][sl_][0];
        bf16x8 al0, al1;
        if constexpr (TERMS == 2) {
            al0 = *(const bf16x8*)&u.s.Al[p][0][sl_][0];
            al1 = *(const bf16x8*)&u.s.Al[p][1][sl_][0];
        }
#pragma unroll
        for (int n = 0; n < NREP; ++n) {
            acc[0][n] = __builtin_amdgcn_mfma_f32_16x16x32_bf16(ah0, bh[n], acc[0][n], 0, 0, 0);
            acc[1][n] = __builtin_amdgcn_mfma_f32_16x16x32_bf16(ah1, bh[n], acc[1][n], 0, 0, 0);
            if constexpr (TERMS == 2) {
                acc[0][n] = __builtin_amdgcn_mfma_f32_16x16x32_bf16(al0, bh[n], acc[0][n], 0, 0, 0);
                acc[1][n] = __builtin_amdgcn_mfma_f32_16x16x32_bf16(al1, bh[n], acc[1][n], 0, 0, 0);
            }
        }
        if (nxt) {
#pragma unroll
            for (int n = 0; n < NREP; ++n) bh[n] = bn[n];  // vmcnt wait here
        }
        p ^= 1;
    }

    // ---- epilogue 1: bf16 feat stores ----
#pragma unroll
    for (int m = 0; m < 2; ++m) {
        int rbase = row0 + m * 16 + kq * 4;
#pragma unroll
        for (int n = 0; n < NREP; ++n) {
            int col = colw + n * 16 + fr;
#pragma unroll
            for (int i = 0; i < 4; ++i) {
                int r = rbase + i;
                if (r < M) featb[(size_t)r * BN + col] = (__bf16)acc[m][n][i];
            }
        }
    }

    // ---- epilogue 2: el/er (wave strip == heads {wid*2, wid*2+1}) ----
    __syncthreads();  // staging dead; ctile (union) safe
#pragma unroll
    for (int m = 0; m < 2; ++m) {
#pragma unroll
        for (int n = 0; n < NREP; ++n)
#pragma unroll
            for (int i = 0; i < 4; ++i)
                u.ctile[wid][kq * 4 + i][n * 16 + fr] = acc[m][n][i];
        if (lane < 32) {
            int r = lane & 15;
            int hh = lane >> 4;
            int h = wid * 2 + hh;
            float sl = 0.f, sr_ = 0.f;
#pragma unroll 8
            for (int d = 0; d < D; ++d) {
                float v = u.ctile[wid][r][hh * D + d];
                sl += v * al[h * D + d];
                sr_ += v * ar[h * D + d];
            }
            int gr = row0 + m * 16 + r;
            if (gr < M) {
                el[(size_t)gr * 8 + h] = sl;
                er[(size_t)gr * 8 + h] = sr_;
            }
        }
    }
}

__device__ __forceinline__ float leaky02(float x) { return x > 0.f ? x : 0.2f * x; }

// ---------------------------------------------------------------------------
// Fused edge-softmax aggregation, one wave per dst node. H=8.
// Phase A: sum-exp + alpha cache in per-wave LDS (CAP=64, fallback).
// Phase B: 4x-unrolled bf16x4 gather (lane owns elems [4*lane,4*lane+4)).
// MODE 0 (D=32): outh = bf16 ELU(sum)   MODE 1 (D=40): outf = head-mean.
// ---------------------------------------------------------------------------
template <int D, int MODE>
__global__ __launch_bounds__(256) void gat_aggregate(
    const __bf16* __restrict__ featb, const float* __restrict__ el,
    const float* __restrict__ er, const int* __restrict__ row_ptr,
    const int* __restrict__ ssrc, __bf16* __restrict__ outh,
    float* __restrict__ outf, int N) {
    constexpr int HD = 8 * D;
    constexpr int TAIL = HD - 256;     // 0 (D=32) or 64 (D=40)
    constexpr int CAP = 64;
    __shared__ float alds[4][CAP][8];
    __shared__ float red[4][MODE ? HD : 1];

    const int wid = threadIdx.x >> 6;
    const int lane = threadIdx.x & 63;
    const int n = blockIdx.x * 4 + wid;
    if (n >= N) return;

    const int beg = row_ptr[n];
    const int end = row_ptr[n + 1];
    const int hl = lane & 7;
    const int sl = lane >> 3;
    const float er_l = er[(size_t)n * 8 + hl];

    // ---- phase A: sum-exp + alpha cache ----
    float s_l = 0.f;
    for (int idx = beg + sl; idx < end; idx += 8) {
        int s = ssrc[idx];
        float e = __expf(leaky02(el[(size_t)s * 8 + hl] + er_l));
        s_l += e;
        int j = idx - beg;
        if (j < CAP) alds[wid][j][hl] = e;
    }
    s_l += __shfl_xor(s_l, 8);
    s_l += __shfl_xor(s_l, 16);
    s_l += __shfl_xor(s_l, 32);
    const float si_l = 1.0f / (s_l + 1e-9f);

    const int hg = (4 * lane) / D;
    int ht = 0;
    if (TAIL) ht = (256 + lane) / D;

    // ---- phase B: unnormalized accumulate, 4x unrolled ----
    float acc[4] = {};
    float acct = 0.f;
    const int capend = (end - beg > CAP) ? beg + CAP : end;
    int idx = beg;
    for (; idx + 4 <= capend; idx += 4) {
        int j = idx - beg;
        int ss[4];
#pragma unroll
        for (int uu = 0; uu < 4; ++uu) ss[uu] = ssrc[idx + uu];
        float w[4], wt[4];
#pragma unroll
        for (int uu = 0; uu < 4; ++uu) {
            w[uu] = alds[wid][j + uu][hg];
            if (TAIL) wt[uu] = alds[wid][j + uu][ht];
        }
        bf16x4 p[4];
        __bf16 pt[4];
#pragma unroll
        for (int uu = 0; uu < 4; ++uu) {
            const __bf16* f = featb + (size_t)ss[uu] * HD;
            p[uu] = *(const bf16x4*)&f[4 * lane];
            if (TAIL) pt[uu] = f[256 + lane];
        }
#pragma unroll
        for (int uu = 0; uu < 4; ++uu) {
#pragma unroll
            for (int e = 0; e < 4; ++e) acc[e] += w[uu] * (float)p[uu][e];
            if (TAIL) acct += wt[uu] * (float)pt[uu];
        }
    }
    for (; idx < capend; ++idx) {
        int j = idx - beg;
        int s = ssrc[idx];
        float w = alds[wid][j][hg];
        const __bf16* f = featb + (size_t)s * HD;
        bf16x4 p = *(const bf16x4*)&f[4 * lane];
#pragma unroll
        for (int e = 0; e < 4; ++e) acc[e] += w * (float)p[e];
        if (TAIL) acct += alds[wid][j][ht] * (float)f[256 + lane];
    }
    for (; idx < end; ++idx) {  // beyond-CAP fallback
        int s = ssrc[idx];
        float a = __expf(leaky02(el[(size_t)s * 8 + hl] + er_l));
        const __bf16* f = featb + (size_t)s * HD;
        float w = __shfl(a, hg);
        bf16x4 p = *(const bf16x4*)&f[4 * lane];
#pragma unroll
        for (int e = 0; e < 4; ++e) acc[e] += w * (float)p[e];
        if (TAIL) acct += __shfl(a, ht) * (float)f[256 + lane];
    }

    // ---- fold in normalization (lane h in [0,8) holds head h's si) ----
    const float sig = __shfl(si_l, hg);
#pragma unroll
    for (int e = 0; e < 4; ++e) acc[e] *= sig;
    if (TAIL) acct *= __shfl(si_l, ht);

    if (MODE == 0) {
        bf16x4 vh;
#pragma unroll
        for (int e = 0; e < 4; ++e) {
            float x = acc[e];
            x = x > 0.f ? x : expm1f(x);
            vh[e] = (__bf16)x;
        }
        *(bf16x4*)&outh[(size_t)n * 256 + 4 * lane] = vh;
    } else {
#pragma unroll
        for (int e = 0; e < 4; ++e) red[wid][4 * lane + e] = acc[e];
        red[wid][256 + lane] = acct;
        if (lane < D) {
            float s = 0.f;
#pragma unroll
            for (int hh = 0; hh < 8; ++hh) s += red[wid][hh * D + lane];
            outf[(size_t)n * D + lane] = s * 0.125f;
        }
    }
}

// ---------------------------------------------------------------------------

extern "C" void kernel_launch(void* const* d_in, const int* in_sizes, int n_in,
                              void* d_out, int out_size, void* d_ws, size_t ws_size,
                              hipStream_t stream) {
    const float* features = (const float*)d_in[0];
    const int* src = (const int*)d_in[1];
    const int* dst = (const int*)d_in[2];
    const float* W1 = (const float*)d_in[3];
    const float* al1 = (const float*)d_in[4];
    const float* ar1 = (const float*)d_in[5];
    const float* W2 = (const float*)d_in[6];
    const float* al2 = (const float*)d_in[7];
    const float* ar2 = (const float*)d_in[8];

    const int N = in_sizes[0] / 512;  // 50000
    const int E = in_sizes[1];        // 800000

    char* ws = (char*)d_ws;
    size_t off = 0;
    auto alloc = [&](size_t bytes) -> void* {
        void* p = ws + off;
        off = (off + bytes + 255) & ~(size_t)255;
        return p;
    };
    __bf16* feat1b = (__bf16*)alloc((size_t)N * 256 * 2);
    __bf16* hbuf = (__bf16*)alloc((size_t)N * 256 * 2);
    __bf16* feat2b = (__bf16*)alloc((size_t)N * 320 * 2);
    float* el1 = (float*)alloc((size_t)N * 8 * 4);
    float* er1 = (float*)alloc((size_t)N * 8 * 4);
    float* el2 = (float*)alloc((size_t)N * 8 * 4);
    float* er2 = (float*)alloc((size_t)N * 8 * 4);
    int* cnt = (int*)alloc((size_t)N * 4);
    int* incl = (int*)alloc((size_t)N * 4);
    int* row_ptr = (int*)alloc((size_t)(N + 1) * 4);
    int* cursor = (int*)alloc((size_t)N * 4);
    int* bsum = (int*)alloc(256 * 4);
    int* boff = (int*)alloc(256 * 4);
    int* ssrc = (int*)alloc((size_t)E * 4);
    __bf16* Bp1h = (__bf16*)alloc((size_t)512 * 256 * 2);
    __bf16* Bp2h = (__bf16*)alloc((size_t)256 * 320 * 2);

    const int NB = (N + 255) / 256;
    const int SZ1 = 512 * 256, SZ2 = 256 * 320;

    // ---- CSR build + weight pack (hist and pack merged: independent) ----
    hipMemsetAsync(cnt, 0, (size_t)N * 4, stream);
    hist_pack_kernel<<<(E + 255) / 256, 256, 0, stream>>>(
        dst, cnt, E, W1, Bp1h, SZ1, 256, W2, Bp2h, SZ2, 320);
    scan_blk<<<NB, 256, 0, stream>>>(cnt, incl, bsum, N);
    scan_top<<<1, 256, 0, stream>>>(bsum, boff, NB);
    scan_fix<<<NB, 256, 0, stream>>>(incl, boff, cnt, row_ptr, cursor, N);
    fill_kernel<<<(E + 255) / 256, 256, 0, stream>>>(src, dst, cursor, ssrc, E);

    const int mblk = (N + 31) / 32;  // 1563

    // ---- layer 1 (2-term split A) ----
    gemm_fused<256, 4, true, 2><<<mblk, 256, 0, stream>>>(
        features, nullptr, Bp1h, al1, ar1, feat1b, el1, er1, N, 512);
    gat_aggregate<32, 0><<<(N + 3) / 4, 256, 0, stream>>>(
        feat1b, el1, er1, row_ptr, ssrc, hbuf, nullptr, N);

    // ---- layer 2 (pure bf16 A) ----
    gemm_fused<320, 5, false, 1><<<mblk, 256, 0, stream>>>(
        nullptr, hbuf, Bp2h, al2, ar2, feat2b, el2, er2, N, 256);
    gat_aggregate<40, 1><<<(N + 3) / 4, 256, 0, stream>>>(
        feat2b, el2, er2, row_ptr, ssrc, nullptr, (float*)d_out, N);
}

// Round 16
// 314.290 us; speedup vs baseline: 1.0389x; 1.0389x over previous
//
#include <hip/hip_runtime.h>
#include <math.h>

typedef float f32x4 __attribute__((ext_vector_type(4)));
typedef __bf16 bf16x2 __attribute__((ext_vector_type(2)));
typedef __bf16 bf16x4 __attribute__((ext_vector_type(4)));
typedef __bf16 bf16x8 __attribute__((ext_vector_type(8)));

// ---------------------------------------------------------------------------
// GAT 2-layer forward.  BEST MEASURED CONFIG (Round-13: 314.5 us, 5.2e-4).
// GEMM layer 1: 2-term split-bf16 MFMA; layer 2: pure bf16. BM=32, 4 waves,
// fragment-major XOR-swizzled LDS A (dbuf), B fragment-major 1KB chunks with
// register prefetch, T4 barrier (lgkmcnt-only + s_barrier), lb(256,4).
// Aggregation: CSR by dst; phase A sum-exp + alpha cache in LDS; phase B
// 4x-unrolled bf16x4 gather (memory-service ceiling, R13 null A/B).
// ---------------------------------------------------------------------------

__global__ void hist_kernel(const int* __restrict__ dst, int* __restrict__ cnt, int E) {
    int e = blockIdx.x * blockDim.x + threadIdx.x;
    if (e < E) atomicAdd(&cnt[dst[e]], 1);
}

__global__ __launch_bounds__(256) void scan_blk(const int* __restrict__ cnt,
                                                int* __restrict__ incl,
                                                int* __restrict__ bsum, int n) {
    __shared__ int sd[256];
    const int t = threadIdx.x;
    int i = blockIdx.x * 256 + t;
    int v = (i < n) ? cnt[i] : 0;
    sd[t] = v;
    __syncthreads();
#pragma unroll
    for (int off = 1; off < 256; off <<= 1) {
        int x = (t >= off) ? sd[t - off] : 0;
        __syncthreads();
        sd[t] += x;
        __syncthreads();
    }
    if (i < n) incl[i] = sd[t];
    if (t == 255) bsum[blockIdx.x] = sd[255];
}

__global__ __launch_bounds__(256) void scan_top(const int* __restrict__ bsum,
                                                int* __restrict__ boff, int nb) {
    __shared__ int sd[256];
    const int t = threadIdx.x;
    int v = (t < nb) ? bsum[t] : 0;
    sd[t] = v;
    __syncthreads();
#pragma unroll
    for (int off = 1; off < 256; off <<= 1) {
        int x = (t >= off) ? sd[t - off] : 0;
        __syncthreads();
        sd[t] += x;
        __syncthreads();
    }
    if (t < nb) boff[t] = sd[t] - v;
}

__global__ void scan_fix(const int* __restrict__ incl, const int* __restrict__ boff,
                         const int* __restrict__ cnt, int* __restrict__ row_ptr,
                         int* __restrict__ cursor, int n) {
    int i = blockIdx.x * blockDim.x + threadIdx.x;
    if (i >= n) return;
    int total = incl[i] + boff[i >> 8];
    row_ptr[i + 1] = total;
    cursor[i] = total - cnt[i];
    if (i == 0) row_ptr[0] = 0;
}

__global__ void fill_kernel(const int* __restrict__ src, const int* __restrict__ dst,
                            int* __restrict__ cursor, int* __restrict__ ssrc, int E) {
    int e = blockIdx.x * blockDim.x + threadIdx.x;
    if (e < E) {
        int pos = atomicAdd(&cursor[dst[e]], 1);
        ssrc[pos] = src[e];
    }
}

// Pack W[K][N] fp32 -> fragment-major bf16 (hi only) 1KB chunks.
__global__ void pack_b_kernel(const float* __restrict__ W, __bf16* __restrict__ Bh,
                              int K, int N) {
    int idx = blockIdx.x * blockDim.x + threadIdx.x;
    if (idx >= K * N) return;
    int e = idx & 7;
    int l = (idx >> 3) & 63;
    int c = idx >> 9;
    int ng = N >> 4;
    int g = c % ng;
    int k0 = (c / ng) << 5;
    int col = g * 16 + (l & 15);
    int k = k0 + ((l >> 4) << 3) + e;
    Bh[idx] = (__bf16)W[(size_t)k * N + col];
}

__device__ __forceinline__ int swz6(int x) { return x ^ (x >> 3); }

// ---------------------------------------------------------------------------
// Split-bf16 MFMA GEMM + fused el/er epilogue. BM=32, 256 thr, 4 waves.
// TERMS=2, FP32A=true : layer 1.  TERMS=1, FP32A=false: layer 2.
// ---------------------------------------------------------------------------
template <int BN, int NREP, bool FP32A, int TERMS>
__global__ __launch_bounds__(256, 4) void gemm_fused(
    const float* __restrict__ Af, const __bf16* __restrict__ Ahg,
    const __bf16* __restrict__ Bph, const float* __restrict__ al,
    const float* __restrict__ ar, __bf16* __restrict__ featb,
    float* __restrict__ el, float* __restrict__ er, int M, int K) {
    constexpr int WN = NREP * 16;  // per-wave strip; BN == 4*WN
    constexpr int D = BN / 8;      // head dim; WN == 2*D (strip = 2 heads)

    struct StageT {
        __bf16 Ah[2][2][64][8];
        __bf16 Al[2][2][64][8];  // used only when TERMS==2
    };
    union Smem {
        StageT s;
        float ctile[4][16][WN + 1];
    };
    __shared__ __align__(16) Smem u;

    const int t = threadIdx.x;
    const int lane = t & 63;
    const int wid = t >> 6;
    const int row0 = blockIdx.x * 32;
    const int colw = wid * WN;
    const int fr = lane & 15;
    const int kq = lane >> 4;
    const int sr = t >> 3;
    const int kc = (t & 7) * 4;
    const int m_s = sr >> 4;
    const int xs = (sr & 15) + 16 * (kc >> 3);
    const int e0 = kc & 7;

    float4 av;
    bf16x4 avh;

    auto loadA = [&](int k0) {
        int gr = row0 + sr;
        if (gr >= M) gr = M - 1;
        if constexpr (FP32A) {
            av = *(const float4*)&Af[(size_t)gr * K + k0 + kc];
        } else {
            avh = *(const bf16x4*)&Ahg[(size_t)gr * K + k0 + kc];
        }
    };
    auto storeA = [&](int p) {
        if constexpr (FP32A) {
            __bf16 h0 = (__bf16)av.x, h1 = (__bf16)av.y, h2 = (__bf16)av.z,
                   h3 = (__bf16)av.w;
            bf16x4 hv = {h0, h1, h2, h3};
            bf16x4 lv = {(__bf16)(av.x - (float)h0), (__bf16)(av.y - (float)h1),
                         (__bf16)(av.z - (float)h2), (__bf16)(av.w - (float)h3)};
            *(bf16x4*)&u.s.Ah[p][m_s][swz6(xs)][e0] = hv;
            *(bf16x4*)&u.s.Al[p][m_s][swz6(xs)][e0] = lv;
        } else {
            *(bf16x4*)&u.s.Ah[p][m_s][swz6(xs)][e0] = avh;
        }
    };
    auto loadB = [&](int k0, bf16x8* b) {
        const int c0 = (k0 >> 5) * (BN >> 4) + wid * NREP;
#pragma unroll
        for (int n = 0; n < NREP; ++n)
            b[n] = *(const bf16x8*)&Bph[(size_t)(c0 + n) * 512 + lane * 8];
    };

    f32x4 acc[2][NREP] = {};
    bf16x8 bh[NREP], bn[NREP];

    loadA(0);
    loadB(0, bh);
    int p = 0;
    for (int k0 = 0; k0 < K; k0 += 32) {
        storeA(p);
        const bool nxt = (k0 + 32 < K);
        if (nxt) {
            loadA(k0 + 32);      // stays in flight across barrier
            loadB(k0 + 32, bn);
        }
        // T4: drain ONLY the LDS staging writes, then raw barrier.
        asm volatile("s_waitcnt lgkmcnt(0)" ::: "memory");
        __builtin_amdgcn_s_barrier();
        const int sl_ = swz6(lane);
        bf16x8 ah0 = *(const bf16x8*)&u.s.Ah[p][0][sl_][0];
        bf16x8 ah1 = *(const bf16x8*)&u.s.Ah[p][1][sl_][0];
        bf16x8 al0, al1;
        if constexpr (TERMS == 2) {
            al0 = *(const bf16x8*)&u.s.Al[p][0][sl_][0];
            al1 = *(const bf16x8*)&u.s.Al[p][1][sl_][0];
        }
#pragma unroll
        for (int n = 0; n < NREP; ++n) {
            acc[0][n] = __builtin_amdgcn_mfma_f32_16x16x32_bf16(ah0, bh[n], acc[0][n], 0, 0, 0);
            acc[1][n] = __builtin_amdgcn_mfma_f32_16x16x32_bf16(ah1, bh[n], acc[1][n], 0, 0, 0);
            if constexpr (TERMS == 2) {
                acc[0][n] = __builtin_amdgcn_mfma_f32_16x16x32_bf16(al0, bh[n], acc[0][n], 0, 0, 0);
                acc[1][n] = __builtin_amdgcn_mfma_f32_16x16x32_bf16(al1, bh[n], acc[1][n], 0, 0, 0);
            }
        }
        if (nxt) {
#pragma unroll
            for (int n = 0; n < NREP; ++n) bh[n] = bn[n];
        }
        p ^= 1;
    }

    // ---- epilogue 1: bf16 feat stores ----
#pragma unroll
    for (int m = 0; m < 2; ++m) {
        int rbase = row0 + m * 16 + kq * 4;
#pragma unroll
        for (int n = 0; n < NREP; ++n) {
            int col = colw + n * 16 + fr;
#pragma unroll
            for (int i = 0; i < 4; ++i) {
                int r = rbase + i;
                if (r < M) featb[(size_t)r * BN + col] = (__bf16)acc[m][n][i];
            }
        }
    }

    // ---- epilogue 2: el/er (wave strip == heads {wid*2, wid*2+1}) ----
    __syncthreads();
#pragma unroll
    for (int m = 0; m < 2; ++m) {
#pragma unroll
        for (int n = 0; n < NREP; ++n)
#pragma unroll
            for (int i = 0; i < 4; ++i)
                u.ctile[wid][kq * 4 + i][n * 16 + fr] = acc[m][n][i];
        if (lane < 32) {
            int r = lane & 15;
            int hh = lane >> 4;
            int h = wid * 2 + hh;
            float sl = 0.f, sr_ = 0.f;
#pragma unroll 8
            for (int d = 0; d < D; ++d) {
                float v = u.ctile[wid][r][hh * D + d];
                sl += v * al[h * D + d];
                sr_ += v * ar[h * D + d];
            }
            int gr = row0 + m * 16 + r;
            if (gr < M) {
                el[(size_t)gr * 8 + h] = sl;
                er[(size_t)gr * 8 + h] = sr_;
            }
        }
    }
}

__device__ __forceinline__ float leaky02(float x) { return x > 0.f ? x : 0.2f * x; }

// ---------------------------------------------------------------------------
// Fused edge-softmax aggregation, one wave per dst node. H=8.
// Phase A: sum-exp + alpha cache in per-wave LDS (CAP=64, fallback).
// Phase B: 4x-unrolled bf16x4 gather (lane owns elems [4*lane,4*lane+4)).
// MODE 0 (D=32): outh = bf16 ELU(sum)   MODE 1 (D=40): outf = head-mean.
// ---------------------------------------------------------------------------
template <int D, int MODE>
__global__ __launch_bounds__(256) void gat_aggregate(
    const __bf16* __restrict__ featb, const float* __restrict__ el,
    const float* __restrict__ er, const int* __restrict__ row_ptr,
    const int* __restrict__ ssrc, __bf16* __restrict__ outh,
    float* __restrict__ outf, int N) {
    constexpr int HD = 8 * D;
    constexpr int TAIL = HD - 256;     // 0 (D=32) or 64 (D=40)
    constexpr int CAP = 64;
    __shared__ float alds[4][CAP][8];
    __shared__ float red[4][MODE ? HD : 1];

    const int wid = threadIdx.x >> 6;
    const int lane = threadIdx.x & 63;
    const int n = blockIdx.x * 4 + wid;
    if (n >= N) return;

    const int beg = row_ptr[n];
    const int end = row_ptr[n + 1];
    const int hl = lane & 7;
    const int sl = lane >> 3;
    const float er_l = er[(size_t)n * 8 + hl];

    // ---- phase A: sum-exp + alpha cache ----
    float s_l = 0.f;
    for (int idx = beg + sl; idx < end; idx += 8) {
        int s = ssrc[idx];
        float e = __expf(leaky02(el[(size_t)s * 8 + hl] + er_l));
        s_l += e;
        int j = idx - beg;
        if (j < CAP) alds[wid][j][hl] = e;
    }
    s_l += __shfl_xor(s_l, 8);
    s_l += __shfl_xor(s_l, 16);
    s_l += __shfl_xor(s_l, 32);
    const float si_l = 1.0f / (s_l + 1e-9f);

    const int hg = (4 * lane) / D;
    int ht = 0;
    if (TAIL) ht = (256 + lane) / D;

    // ---- phase B: unnormalized accumulate, 4x unrolled ----
    float acc[4] = {};
    float acct = 0.f;
    const int capend = (end - beg > CAP) ? beg + CAP : end;
    int idx = beg;
    for (; idx + 4 <= capend; idx += 4) {
        int j = idx - beg;
        int ss[4];
#pragma unroll
        for (int uu = 0; uu < 4; ++uu) ss[uu] = ssrc[idx + uu];
        float w[4], wt[4];
#pragma unroll
        for (int uu = 0; uu < 4; ++uu) {
            w[uu] = alds[wid][j + uu][hg];
            if (TAIL) wt[uu] = alds[wid][j + uu][ht];
        }
        bf16x4 p[4];
        __bf16 pt[4];
#pragma unroll
        for (int uu = 0; uu < 4; ++uu) {
            const __bf16* f = featb + (size_t)ss[uu] * HD;
            p[uu] = *(const bf16x4*)&f[4 * lane];
            if (TAIL) pt[uu] = f[256 + lane];
        }
#pragma unroll
        for (int uu = 0; uu < 4; ++uu) {
#pragma unroll
            for (int e = 0; e < 4; ++e) acc[e] += w[uu] * (float)p[uu][e];
            if (TAIL) acct += wt[uu] * (float)pt[uu];
        }
    }
    for (; idx < capend; ++idx) {
        int j = idx - beg;
        int s = ssrc[idx];
        float w = alds[wid][j][hg];
        const __bf16* f = featb + (size_t)s * HD;
        bf16x4 p = *(const bf16x4*)&f[4 * lane];
#pragma unroll
        for (int e = 0; e < 4; ++e) acc[e] += w * (float)p[e];
        if (TAIL) acct += alds[wid][j][ht] * (float)f[256 + lane];
    }
    for (; idx < end; ++idx) {  // beyond-CAP fallback
        int s = ssrc[idx];
        float a = __expf(leaky02(el[(size_t)s * 8 + hl] + er_l));
        const __bf16* f = featb + (size_t)s * HD;
        float w = __shfl(a, hg);
        bf16x4 p = *(const bf16x4*)&f[4 * lane];
#pragma unroll
        for (int e = 0; e < 4; ++e) acc[e] += w * (float)p[e];
        if (TAIL) acct += __shfl(a, ht) * (float)f[256 + lane];
    }

    // ---- fold in normalization (lane h in [0,8) holds head h's si) ----
    const float sig = __shfl(si_l, hg);
#pragma unroll
    for (int e = 0; e < 4; ++e) acc[e] *= sig;
    if (TAIL) acct *= __shfl(si_l, ht);

    if (MODE == 0) {
        bf16x4 vh;
#pragma unroll
        for (int e = 0; e < 4; ++e) {
            float x = acc[e];
            x = x > 0.f ? x : expm1f(x);
            vh[e] = (__bf16)x;
        }
        *(bf16x4*)&outh[(size_t)n * 256 + 4 * lane] = vh;
    } else {
#pragma unroll
        for (int e = 0; e < 4; ++e) red[wid][4 * lane + e] = acc[e];
        red[wid][256 + lane] = acct;
        if (lane < D) {
            float s = 0.f;
#pragma unroll
            for (int hh = 0; hh < 8; ++hh) s += red[wid][hh * D + lane];
            outf[(size_t)n * D + lane] = s * 0.125f;
        }
    }
}

// ---------------------------------------------------------------------------

extern "C" void kernel_launch(void* const* d_in, const int* in_sizes, int n_in,
                              void* d_out, int out_size, void* d_ws, size_t ws_size,
                              hipStream_t stream) {
    const float* features = (const float*)d_in[0];
    const int* src = (const int*)d_in[1];
    const int* dst = (const int*)d_in[2];
    const float* W1 = (const float*)d_in[3];
    const float* al1 = (const float*)d_in[4];
    const float* ar1 = (const float*)d_in[5];
    const float* W2 = (const float*)d_in[6];
    const float* al2 = (const float*)d_in[7];
    const float* ar2 = (const float*)d_in[8];

    const int N = in_sizes[0] / 512;  // 50000
    const int E = in_sizes[1];        // 800000

    char* ws = (char*)d_ws;
    size_t off = 0;
    auto alloc = [&](size_t bytes) -> void* {
        void* p = ws + off;
        off = (off + bytes + 255) & ~(size_t)255;
        return p;
    };
    __bf16* feat1b = (__bf16*)alloc((size_t)N * 256 * 2);
    __bf16* hbuf = (__bf16*)alloc((size_t)N * 256 * 2);
    __bf16* feat2b = (__bf16*)alloc((size_t)N * 320 * 2);
    float* el1 = (float*)alloc((size_t)N * 8 * 4);
    float* er1 = (float*)alloc((size_t)N * 8 * 4);
    float* el2 = (float*)alloc((size_t)N * 8 * 4);
    float* er2 = (float*)alloc((size_t)N * 8 * 4);
    int* cnt = (int*)alloc((size_t)N * 4);
    int* incl = (int*)alloc((size_t)N * 4);
    int* row_ptr = (int*)alloc((size_t)(N + 1) * 4);
    int* cursor = (int*)alloc((size_t)N * 4);
    int* bsum = (int*)alloc(256 * 4);
    int* boff = (int*)alloc(256 * 4);
    int* ssrc = (int*)alloc((size_t)E * 4);
    __bf16* Bp1h = (__bf16*)alloc((size_t)512 * 256 * 2);
    __bf16* Bp2h = (__bf16*)alloc((size_t)256 * 320 * 2);

    const int NB = (N + 255) / 256;

    // ---- CSR build ----
    hipMemsetAsync(cnt, 0, (size_t)N * 4, stream);
    hist_kernel<<<(E + 255) / 256, 256, 0, stream>>>(dst, cnt, E);
    scan_blk<<<NB, 256, 0, stream>>>(cnt, incl, bsum, N);
    scan_top<<<1, 256, 0, stream>>>(bsum, boff, NB);
    scan_fix<<<NB, 256, 0, stream>>>(incl, boff, cnt, row_ptr, cursor, N);
    fill_kernel<<<(E + 255) / 256, 256, 0, stream>>>(src, dst, cursor, ssrc, E);

    // ---- weight pack (fragment-major, hi only) ----
    pack_b_kernel<<<(512 * 256 + 255) / 256, 256, 0, stream>>>(W1, Bp1h, 512, 256);
    pack_b_kernel<<<(256 * 320 + 255) / 256, 256, 0, stream>>>(W2, Bp2h, 256, 320);

    const int mblk = (N + 31) / 32;  // 1563

    // ---- layer 1 (2-term split A) ----
    gemm_fused<256, 4, true, 2><<<mblk, 256, 0, stream>>>(
        features, nullptr, Bp1h, al1, ar1, feat1b, el1, er1, N, 512);
    gat_aggregate<32, 0><<<(N + 3) / 4, 256, 0, stream>>>(
        feat1b, el1, er1, row_ptr, ssrc, hbuf, nullptr, N);

    // ---- layer 2 (pure bf16 A) ----
    gemm_fused<320, 5, false, 1><<<mblk, 256, 0, stream>>>(
        nullptr, hbuf, Bp2h, al2, ar2, feat2b, el2, er2, N, 256);
    gat_aggregate<40, 1><<<(N + 3) / 4, 256, 0, stream>>>(
        feat2b, el2, er2, row_ptr, ssrc, nullptr, (float*)d_out, N);
}